// Round 6
// baseline (406.850 us; speedup 1.0000x reference)
//
#include <hip/hip_runtime.h>
#include <hip/hip_fp16.h>
#include <math.h>

// GCN: h0 = lrelu(Agg(x@W0)+b0); h1 = lrelu(Agg(h0@W1)+b1); out = sigmoid(h1[idx]@Wm+bm)
// Agg (sym-norm + self loops): agg[d] = dinv[d] * ( sum_{e:dst=d} hs[src] + hs[d] ),
// hs = h * dinv[row], stored FP16 row-major [N][64].
// Layer-2 aggregation only for the 20k selected nodes (fused head in k_aggout).
// GEMM: fp16 MFMA 16x16x32, fp32 accum.
// R1: predicated batch loop -> 47.4us agg1.
// R2 (reverted): channel-quarter split: L2-resident gathers but 2x slower ->
//     limiter is per-instr address divergence, not L2-miss BW.
// R3/R4: coalesced esB preload + __shfl distribution, 8 gathers in flight ->
//     agg1 47.4 -> <40us. agg1 now ~5.5TB/s effective = near cache ceiling.
// R5: NPART 64->256 for binned CSR build (scatter 41 -> ~12us).
// R6: direct-atomic CSR build. 1.6M global atomics on 400KB L2-resident tables
//     are cheap on CDNA4; drop {part_hist, part_scatter, bsort, 400k scans} ->
//     {memset, k_deg, 100k scans (also emit dinv+cursor), k_scatterd}. Removes
//     esA intermediate (19MB traffic) + bsort. Edge order within node becomes
//     atomic-order (fp32 re-association only).

typedef _Float16 h8 __attribute__((ext_vector_type(8)));
typedef float f4v __attribute__((ext_vector_type(4)));

__device__ __forceinline__ float lrelu(float x) { return x > 0.0f ? x : 0.01f * x; }

// ---------- degree histogram: 4-edge ILP global atomics ----------

__global__ __launch_bounds__(256) void k_deg(const int* __restrict__ dst, int E,
                                             int* __restrict__ deg) {
    int tid = blockIdx.x * blockDim.x + threadIdx.x;
    int stride = gridDim.x * blockDim.x;
    int cnt4 = E >> 2;
    for (int i = tid; i < cnt4; i += stride) {
        int4 d = *(const int4*)(dst + i * 4);
        atomicAdd(&deg[d.x], 1);
        atomicAdd(&deg[d.y], 1);
        atomicAdd(&deg[d.z], 1);
        atomicAdd(&deg[d.w], 1);
    }
    if (tid < (E & 3)) atomicAdd(&deg[dst[cnt4 * 4 + tid]], 1);
}

// ---------- scan over N (blocksum -> single-block scan -> per-block) ----------

__global__ void k_blocksum(const int* __restrict__ cnt, int N, int* __restrict__ bsum) {
    __shared__ int sm[256];
    int b = blockIdx.x, t = threadIdx.x;
    int base = b * 1024 + t * 4;
    int s = 0;
#pragma unroll
    for (int i = 0; i < 4; ++i) { int j = base + i; if (j < N) s += cnt[j]; }
    sm[t] = s; __syncthreads();
    for (int off = 128; off > 0; off >>= 1) {
        if (t < off) sm[t] += sm[t + off];
        __syncthreads();
    }
    if (t == 0) bsum[b] = sm[0];
}

__global__ void k_scan_bsum(int* __restrict__ bsum, int nb, int* __restrict__ offN) {
    __shared__ int sm[1024];
    int t = threadIdx.x;
    int v = (t < nb) ? bsum[t] : 0;
    sm[t] = v; __syncthreads();
    for (int d = 1; d < 1024; d <<= 1) {
        int add = (t >= d) ? sm[t - d] : 0;
        __syncthreads();
        sm[t] += add;
        __syncthreads();
    }
    if (t < nb) bsum[t] = sm[t] - v;       // exclusive
    if (t == nb - 1) *offN = sm[t];        // total == E
}

// also emits cursor copy (scatter destroys it) and dinv = rsqrt(deg+1)
__global__ void k_scan_block(const int* __restrict__ cnt, const int* __restrict__ bsum,
                             int* __restrict__ off, int* __restrict__ cur,
                             float* __restrict__ dinv, int N) {
    __shared__ int sm[256];
    int b = blockIdx.x, t = threadIdx.x;
    int base = b * 1024 + t * 4;
    int v[4];
#pragma unroll
    for (int i = 0; i < 4; ++i) { int j = base + i; v[i] = (j < N) ? cnt[j] : 0; }
    int tsum = v[0] + v[1] + v[2] + v[3];
    sm[t] = tsum; __syncthreads();
    for (int d = 1; d < 256; d <<= 1) {
        int val = (t >= d) ? sm[t - d] : 0;
        __syncthreads();
        sm[t] += val;
        __syncthreads();
    }
    int run = sm[t] - tsum + bsum[b];
#pragma unroll
    for (int i = 0; i < 4; ++i) {
        int j = base + i;
        if (j < N) {
            off[j] = run;
            cur[j] = run;
            dinv[j] = rsqrtf((float)v[i] + 1.0f);  // +1 self loop
        }
        run += v[i];
    }
}

// ---------- direct scatter: pos = atomicAdd(cursor[dst]); esB[pos] = src ----------

__global__ __launch_bounds__(256) void k_scatterd(const int* __restrict__ src,
                                                  const int* __restrict__ dst, int E,
                                                  int* __restrict__ cur,
                                                  int* __restrict__ esB) {
    int tid = blockIdx.x * blockDim.x + threadIdx.x;
    int stride = gridDim.x * blockDim.x;
    int cnt4 = E >> 2;
    for (int i = tid; i < cnt4; i += stride) {
        int e = i * 4;
        int4 d = *(const int4*)(dst + e);
        int4 s = *(const int4*)(src + e);
        int p0 = atomicAdd(&cur[d.x], 1);
        int p1 = atomicAdd(&cur[d.y], 1);
        int p2 = atomicAdd(&cur[d.z], 1);
        int p3 = atomicAdd(&cur[d.w], 1);
        esB[p0] = s.x;
        esB[p1] = s.y;
        esB[p2] = s.z;
        esB[p3] = s.w;
    }
    if (tid < (E & 3)) {
        int e = cnt4 * 4 + tid;
        int pos = atomicAdd(&cur[dst[e]], 1);
        esB[pos] = src[e];
    }
}

// ---------- GEMM: fp16 MFMA 16x16x32, fp32 accumulate ----------
// Block 256 = 4 waves; 64 rows/block; wave wv -> rows [16wv,16wv+16), all 64 cols.

template <int K, typename AT>
__global__ __launch_bounds__(256) void k_gemm(const AT* __restrict__ A,
                                              const float* __restrict__ W,
                                              const float* __restrict__ dinv,
                                              __half* __restrict__ hout, int N) {
    constexpr int ASTR = K + 8;
    __shared__ _Float16 a16[64 * ASTR];
    __shared__ _Float16 wt16[64 * ASTR];
    int t = threadIdx.x, lane = t & 63, wv = t >> 6;
    int rowBase = blockIdx.x * 64;

    // stage A rows -> fp16 (4 elems per thread-iter)
#pragma unroll
    for (int i = 0; i < K / 16; ++i) {
        int g = i * 256 + t;
        int r = g / (K / 4), kq = g % (K / 4);
        int gr = rowBase + r; if (gr >= N) gr = N - 1;
        _Float16* p = a16 + r * ASTR + kq * 4;
        if constexpr (sizeof(AT) == 4) {
            float4 v = *(const float4*)((const float*)A + (size_t)gr * K + kq * 4);
            *(__half2*)(p)     = __floats2half2_rn(v.x, v.y);
            *(__half2*)(p + 2) = __floats2half2_rn(v.z, v.w);
        } else {
            *(uint2*)p = *(const uint2*)((const __half*)A + (size_t)gr * K + kq * 4);
        }
    }
    // stage W^T -> fp16
#pragma unroll
    for (int i = 0; i < K / 16; ++i) {
        int g = i * 256 + t;
        int k = g >> 4, nq = g & 15;
        float4 v = *(const float4*)(W + (size_t)k * 64 + nq * 4);
        wt16[(nq * 4 + 0) * ASTR + k] = (_Float16)v.x;
        wt16[(nq * 4 + 1) * ASTR + k] = (_Float16)v.y;
        wt16[(nq * 4 + 2) * ASTR + k] = (_Float16)v.z;
        wt16[(nq * 4 + 3) * ASTR + k] = (_Float16)v.w;
    }
    __syncthreads();

    int m = lane & 15, q = lane >> 4;
    f4v acc[4] = {{0,0,0,0},{0,0,0,0},{0,0,0,0},{0,0,0,0}};
    const _Float16* arow = a16 + (wv * 16 + m) * ASTR + q * 8;
#pragma unroll
    for (int kt = 0; kt < K / 32; ++kt) {
        h8 af = *(const h8*)(arow + kt * 32);
#pragma unroll
        for (int nt = 0; nt < 4; ++nt) {
            h8 bf = *(const h8*)(wt16 + (nt * 16 + m) * ASTR + kt * 32 + q * 8);
            acc[nt] = __builtin_amdgcn_mfma_f32_16x16x32_f16(af, bf, acc[nt], 0, 0, 0);
        }
    }

    // epilogue: lane holds D[row=q*4+reg][col=nt*16+m]
    int r0 = rowBase + wv * 16 + q * 4;
#pragma unroll
    for (int reg = 0; reg < 4; ++reg) {
        int row = r0 + reg;
        if (row >= N) continue;
        float dv = dinv[row];
#pragma unroll
        for (int nt = 0; nt < 4; ++nt)
            hout[(size_t)row * 64 + nt * 16 + m] = (__half)(acc[nt][reg] * dv);
    }
}

// ---------- layer-1 aggregation: wave per node, fuses b0+lrelu, writes fp16 ----------
// lane = (qt, l16): group qt gathers edge rows; 16 lanes x uint2 = 128B per row.
// R3/R4: preload up to 64 edge indices with ONE coalesced esB load, distribute via
// __shfl; degree-branched chunks keep 4/8/8+8 gathers in flight, no esB in chain.

__global__ __launch_bounds__(256) void k_agg1(const int* __restrict__ off,
                                              const int* __restrict__ esB,
                                              const float* __restrict__ dinv,
                                              const __half* __restrict__ hs,
                                              const float* __restrict__ b0,
                                              __half* __restrict__ aout, int N) {
    int lane = threadIdx.x & 63;
    int node = (blockIdx.x * blockDim.x + threadIdx.x) >> 6;
    if (node >= N) return;
    int qt = lane >> 4, l16 = lane & 15;
    int beg = off[node], end = off[node + 1];
    float dv = dinv[node];                       // hoisted
    float4 b = *(const float4*)(b0 + l16 * 4);   // hoisted

    float ax = 0, ay = 0, az = 0, aw = 0;
    auto ld = [&](int s) { return *(const uint2*)(hs + (size_t)s * 64 + l16 * 4); };
    auto acc4 = [&](uint2 u) {
        float2 f0 = __half22float2(*(__half2*)&u.x);
        float2 f1 = __half22float2(*(__half2*)&u.y);
        ax += f0.x; ay += f0.y; az += f1.x; aw += f1.y;
    };
    if (qt == 0) acc4(ld(node));  // self loop (issued first, overlaps edge idx load)

    for (int base = beg; base < end; base += 64) {
        int nb = min(end - base, 64);                   // wave-uniform
        int myIdx = esB[min(base + lane, end - 1)];     // ONE coalesced idx load
        if (nb <= 16) {                                  // 4 gathers/group in flight
            int s0 = __shfl(myIdx, min(qt,      nb - 1));
            int s1 = __shfl(myIdx, min(qt + 4,  nb - 1));
            int s2 = __shfl(myIdx, min(qt + 8,  nb - 1));
            int s3 = __shfl(myIdx, min(qt + 12, nb - 1));
            uint2 u0 = ld(s0), u1 = ld(s1), u2 = ld(s2), u3 = ld(s3);
            if (qt      < nb) acc4(u0);
            if (qt + 4  < nb) acc4(u1);
            if (qt + 8  < nb) acc4(u2);
            if (qt + 12 < nb) acc4(u3);
        } else {                                         // 8 gathers/group in flight
            int s0 = __shfl(myIdx, min(qt,      nb - 1));
            int s1 = __shfl(myIdx, min(qt + 4,  nb - 1));
            int s2 = __shfl(myIdx, min(qt + 8,  nb - 1));
            int s3 = __shfl(myIdx, min(qt + 12, nb - 1));
            int s4 = __shfl(myIdx, min(qt + 16, nb - 1));
            int s5 = __shfl(myIdx, min(qt + 20, nb - 1));
            int s6 = __shfl(myIdx, min(qt + 24, nb - 1));
            int s7 = __shfl(myIdx, min(qt + 28, nb - 1));
            uint2 u0 = ld(s0), u1 = ld(s1), u2 = ld(s2), u3 = ld(s3);
            uint2 u4 = ld(s4), u5 = ld(s5), u6 = ld(s6), u7 = ld(s7);
            acc4(u0);                                    // qt < 4 <= 16 < nb: safe
            if (qt + 4  < nb) acc4(u1);
            if (qt + 8  < nb) acc4(u2);
            if (qt + 12 < nb) acc4(u3);
            if (qt + 16 < nb) acc4(u4);
            if (qt + 20 < nb) acc4(u5);
            if (qt + 24 < nb) acc4(u6);
            if (qt + 28 < nb) acc4(u7);
            if (nb > 32) {                               // second 8-chunk (deg 33..64)
                int t0 = __shfl(myIdx, min(qt + 32, nb - 1));
                int t1 = __shfl(myIdx, min(qt + 36, nb - 1));
                int t2 = __shfl(myIdx, min(qt + 40, nb - 1));
                int t3 = __shfl(myIdx, min(qt + 44, nb - 1));
                int t4 = __shfl(myIdx, min(qt + 48, nb - 1));
                int t5 = __shfl(myIdx, min(qt + 52, nb - 1));
                int t6 = __shfl(myIdx, min(qt + 56, nb - 1));
                int t7 = __shfl(myIdx, min(qt + 60, nb - 1));
                uint2 v0 = ld(t0), v1 = ld(t1), v2 = ld(t2), v3 = ld(t3);
                uint2 v4 = ld(t4), v5 = ld(t5), v6 = ld(t6), v7 = ld(t7);
                if (qt + 32 < nb) acc4(v0);              // predicate slot qt+32
                if (qt + 36 < nb) acc4(v1);
                if (qt + 40 < nb) acc4(v2);
                if (qt + 44 < nb) acc4(v3);
                if (qt + 48 < nb) acc4(v4);
                if (qt + 52 < nb) acc4(v5);
                if (qt + 56 < nb) acc4(v6);
                if (qt + 60 < nb) acc4(v7);
            }
        }
    }

#pragma unroll
    for (int d = 16; d <= 32; d <<= 1) {
        ax += __shfl_xor(ax, d); ay += __shfl_xor(ay, d);
        az += __shfl_xor(az, d); aw += __shfl_xor(aw, d);
    }
    if (qt == 0) {
        float ox = lrelu(ax * dv + b.x), oy = lrelu(ay * dv + b.y);
        float oz = lrelu(az * dv + b.z), ow = lrelu(aw * dv + b.w);
        uint2 u;
        *(__half2*)&u.x = __floats2half2_rn(ox, oy);
        *(__half2*)&u.y = __floats2half2_rn(oz, ow);
        *(uint2*)(aout + (size_t)node * 64 + l16 * 4) = u;
    }
}

// ---------- fused selected-node layer-2 agg + b1 + lrelu + head + sigmoid ----------
// wave per output slot: node=idx[wv]; gather its edges only (~20% of E total).

__global__ __launch_bounds__(256) void k_aggout(const int* __restrict__ idx,
                                                const int* __restrict__ off,
                                                const int* __restrict__ esB,
                                                const float* __restrict__ dinv,
                                                const __half* __restrict__ hs,
                                                const float* __restrict__ b1,
                                                const float* __restrict__ Wm,
                                                const float* __restrict__ bm,
                                                float* __restrict__ out, int NSEL) {
    int lane = threadIdx.x & 63;
    int wv = (blockIdx.x * blockDim.x + threadIdx.x) >> 6;
    if (wv >= NSEL) return;
    int node = idx[wv];
    int qt = lane >> 4, l16 = lane & 15;
    int beg = off[node], end = off[node + 1];
    float dv = dinv[node];                       // hoisted
    float4 b = *(const float4*)(b1 + l16 * 4);   // hoisted

    float ax = 0, ay = 0, az = 0, aw = 0;
    auto ld = [&](int s) { return *(const uint2*)(hs + (size_t)s * 64 + l16 * 4); };
    auto acc4 = [&](uint2 u) {
        float2 f0 = __half22float2(*(__half2*)&u.x);
        float2 f1 = __half22float2(*(__half2*)&u.y);
        ax += f0.x; ay += f0.y; az += f1.x; aw += f1.y;
    };
    if (qt == 0) acc4(ld(node));  // self loop

    for (int base = beg; base < end; base += 64) {
        int nb = min(end - base, 64);
        int myIdx = esB[min(base + lane, end - 1)];
        if (nb <= 16) {
            int s0 = __shfl(myIdx, min(qt,      nb - 1));
            int s1 = __shfl(myIdx, min(qt + 4,  nb - 1));
            int s2 = __shfl(myIdx, min(qt + 8,  nb - 1));
            int s3 = __shfl(myIdx, min(qt + 12, nb - 1));
            uint2 u0 = ld(s0), u1 = ld(s1), u2 = ld(s2), u3 = ld(s3);
            if (qt      < nb) acc4(u0);
            if (qt + 4  < nb) acc4(u1);
            if (qt + 8  < nb) acc4(u2);
            if (qt + 12 < nb) acc4(u3);
        } else {
            int s0 = __shfl(myIdx, min(qt,      nb - 1));
            int s1 = __shfl(myIdx, min(qt + 4,  nb - 1));
            int s2 = __shfl(myIdx, min(qt + 8,  nb - 1));
            int s3 = __shfl(myIdx, min(qt + 12, nb - 1));
            int s4 = __shfl(myIdx, min(qt + 16, nb - 1));
            int s5 = __shfl(myIdx, min(qt + 20, nb - 1));
            int s6 = __shfl(myIdx, min(qt + 24, nb - 1));
            int s7 = __shfl(myIdx, min(qt + 28, nb - 1));
            uint2 u0 = ld(s0), u1 = ld(s1), u2 = ld(s2), u3 = ld(s3);
            uint2 u4 = ld(s4), u5 = ld(s5), u6 = ld(s6), u7 = ld(s7);
            acc4(u0);
            if (qt + 4  < nb) acc4(u1);
            if (qt + 8  < nb) acc4(u2);
            if (qt + 12 < nb) acc4(u3);
            if (qt + 16 < nb) acc4(u4);
            if (qt + 20 < nb) acc4(u5);
            if (qt + 24 < nb) acc4(u6);
            if (qt + 28 < nb) acc4(u7);
            if (nb > 32) {
                int t0 = __shfl(myIdx, min(qt + 32, nb - 1));
                int t1 = __shfl(myIdx, min(qt + 36, nb - 1));
                int t2 = __shfl(myIdx, min(qt + 40, nb - 1));
                int t3 = __shfl(myIdx, min(qt + 44, nb - 1));
                int t4 = __shfl(myIdx, min(qt + 48, nb - 1));
                int t5 = __shfl(myIdx, min(qt + 52, nb - 1));
                int t6 = __shfl(myIdx, min(qt + 56, nb - 1));
                int t7 = __shfl(myIdx, min(qt + 60, nb - 1));
                uint2 v0 = ld(t0), v1 = ld(t1), v2 = ld(t2), v3 = ld(t3);
                uint2 v4 = ld(t4), v5 = ld(t5), v6 = ld(t6), v7 = ld(t7);
                if (qt + 32 < nb) acc4(v0);
                if (qt + 36 < nb) acc4(v1);
                if (qt + 40 < nb) acc4(v2);
                if (qt + 44 < nb) acc4(v3);
                if (qt + 48 < nb) acc4(v4);
                if (qt + 52 < nb) acc4(v5);
                if (qt + 56 < nb) acc4(v6);
                if (qt + 60 < nb) acc4(v7);
            }
        }
    }

#pragma unroll
    for (int d = 16; d <= 32; d <<= 1) {  // all lanes end with full sums
        ax += __shfl_xor(ax, d); ay += __shfl_xor(ay, d);
        az += __shfl_xor(az, d); aw += __shfl_xor(aw, d);
    }

    float4 hsel;
    hsel.x = lrelu(ax * dv + b.x); hsel.y = lrelu(ay * dv + b.y);
    hsel.z = lrelu(az * dv + b.z); hsel.w = lrelu(aw * dv + b.w);
    if (qt == 0) *(float4*)(out + (size_t)wv * 64 + l16 * 4) = hsel;

    // head: p[o] = sum_c hsel_c * Wm[c][o]; channels 4*l16..4*l16+3 on each lane
    const float* wr = Wm + (size_t)(4 * l16) * 5;
#pragma unroll
    for (int o = 0; o < 5; ++o) {
        float p = hsel.x * wr[o] + hsel.y * wr[5 + o] +
                  hsel.z * wr[10 + o] + hsel.w * wr[15 + o];
        p += __shfl_xor(p, 1); p += __shfl_xor(p, 2);
        p += __shfl_xor(p, 4); p += __shfl_xor(p, 8);
        if (lane == 0)
            out[(size_t)NSEL * 64 + (size_t)wv * 5 + o] =
                1.0f / (1.0f + expf(-(p + bm[o])));
    }
}

extern "C" void kernel_launch(void* const* d_in, const int* in_sizes, int n_in,
                              void* d_out, int out_size, void* d_ws, size_t ws_size,
                              hipStream_t stream) {
    const float* x   = (const float*)d_in[0];
    const int*   ei  = (const int*)d_in[1];
    const int*   idx = (const int*)d_in[2];
    const float* W0  = (const float*)d_in[3];
    const float* b0  = (const float*)d_in[4];
    const float* W1  = (const float*)d_in[5];
    const float* b1  = (const float*)d_in[6];
    const float* Wm  = (const float*)d_in[7];
    const float* bm  = (const float*)d_in[8];

    int N    = in_sizes[0] / 128;
    int E    = in_sizes[1] / 2;
    int NSEL = in_sizes[2];
    const int* src = ei;
    const int* dst = ei + E;

    char* w = (char*)d_ws;
    size_t Na  = ((size_t)N + 1023) & ~(size_t)1023;
    size_t Ea  = ((size_t)E + 1023) & ~(size_t)1023;
    float*  dinv  = (float*)w;                w += Na * 4;
    int*    deg   = (int*)w;                  w += Na * 4;
    int*    off   = (int*)w;                  w += (Na + 1024) * 4;
    int*    cur   = (int*)w;                  w += Na * 4;
    int*    bsum  = (int*)w;                  w += 1024 * 4;
    int*    esB   = (int*)w;                  w += Ea * 4;
    __half* hs16  = (__half*)w;               w += (size_t)N * 64 * 2;  // h*dinv (layer in/out)
    __half* a16g  = (__half*)w;                                        // lrelu(agg1+b0), fp16

    int nbp = (N + 1023) / 1024;  // scan blocks over N (<= 1024)

    hipMemsetAsync(deg, 0, (size_t)N * 4, stream);

    int ek_blocks = min(2048, (E / 4 + 255) / 256);
    k_deg<<<ek_blocks, 256, 0, stream>>>(dst, E, deg);
    k_blocksum<<<nbp, 256, 0, stream>>>(deg, N, bsum);
    k_scan_bsum<<<1, 1024, 0, stream>>>(bsum, nbp, off + N);
    k_scan_block<<<nbp, 256, 0, stream>>>(deg, bsum, off, cur, dinv, N);
    k_scatterd<<<ek_blocks, 256, 0, stream>>>(src, dst, E, cur, esB);

    int gemm_blocks = (N + 63) / 64;
    int agg_blocks  = (N + 3) / 4;

    k_gemm<128, float><<<gemm_blocks, 256, 0, stream>>>(x, W0, dinv, hs16, N);
    k_agg1<<<agg_blocks, 256, 0, stream>>>(off, esB, dinv, hs16, b0, a16g, N);
    k_gemm<64, __half><<<gemm_blocks, 256, 0, stream>>>(a16g, W1, dinv, hs16, N);
    k_aggout<<<(NSEL + 3) / 4, 256, 0, stream>>>(idx, off, esB, dinv, hs16, b1, Wm, bm,
                                                 (float*)d_out, NSEL);
}

// Round 7
// 240.650 us; speedup vs baseline: 1.6906x; 1.6906x over previous
//
#include <hip/hip_runtime.h>
#include <hip/hip_fp16.h>
#include <math.h>

// GCN: h0 = lrelu(Agg(x@W0)+b0); h1 = lrelu(Agg(h0@W1)+b1); out = sigmoid(h1[idx]@Wm+bm)
// Agg (sym-norm + self loops): agg[d] = dinv[d] * ( sum_{e:dst=d} hs[src] + hs[d] ),
// hs = h * dinv[row], stored FP16 row-major [N][64].
// Layer-2 aggregation only for the 20k selected nodes (fused head in k_aggout).
// CSR build: partition-binned scatter + per-bucket LDS counting sort.
// GEMM: fp16 MFMA 16x16x32, fp32 accum.
// R1: predicated batch loop -> 47.4us agg1.
// R2 (reverted): channel-quarter split: L2-resident gathers (FETCH 86->48MB) but
//     2x SLOWER -> limiter is per-instr address divergence, not L2-miss BW.
// R3/R4: coalesced esB preload + __shfl distribution, 8 gathers in flight ->
//     agg1 47.4 -> <40us.
// R5: NPART 64->256 for binned CSR build (scatter 41 -> ~12us). 242.5us total.
// R6 (reverted): direct-atomic CSR build: esB 4B stores to random addresses ->
//     WRITE_SIZE 107MB vs 6.4 ideal (16x line amplification), scatter 141us.
//     Binned build exists to keep writes bucket-local; line locality matters on
//     the WRITE side too, not just gathers (R2's lesson, mirrored).
// R7: revert to R5 exactly (verified best).

#define NPART 256
#define MAXB 2048  // max dst-buckets (N <= 131072)

typedef _Float16 h8 __attribute__((ext_vector_type(8)));
typedef float f4v __attribute__((ext_vector_type(4)));

__device__ __forceinline__ float lrelu(float x) { return x > 0.0f ? x : 0.01f * x; }

// ---------- partitioned binning (1024 threads, 4-edge ILP) ----------

__global__ __launch_bounds__(1024) void k_part_hist(const int* __restrict__ dst, int E,
                                                    int B, int* __restrict__ phist) {
    __shared__ int scnt[MAXB];
    int t = threadIdx.x, p = blockIdx.x;
    for (int i = t; i < B; i += 1024) scnt[i] = 0;
    __syncthreads();
    int ep = (((E + NPART - 1) / NPART) + 3) & ~3;
    int beg = p * ep, endi = min(E, beg + ep);
    int cnt4 = (endi - beg) >> 2;
    for (int i = t; i < cnt4; i += 1024) {
        int4 d = *(const int4*)(dst + beg + i * 4);
        atomicAdd(&scnt[d.x >> 6], 1);
        atomicAdd(&scnt[d.y >> 6], 1);
        atomicAdd(&scnt[d.z >> 6], 1);
        atomicAdd(&scnt[d.w >> 6], 1);
    }
    int rem = (endi - beg) & 3;
    if (t < rem) atomicAdd(&scnt[dst[beg + cnt4 * 4 + t] >> 6], 1);
    __syncthreads();
    for (int i = t; i < B; i += 1024) phist[i * NPART + p] = scnt[i];
}

__global__ __launch_bounds__(1024) void k_part_scatter(const int* __restrict__ src,
                                                       const int* __restrict__ dst, int E,
                                                       int B, const int* __restrict__ pbase,
                                                       int* __restrict__ esA) {
    __shared__ int sbase[MAXB];
    int t = threadIdx.x, p = blockIdx.x;
    for (int i = t; i < B; i += 1024) sbase[i] = pbase[i * NPART + p];
    __syncthreads();
    int ep = (((E + NPART - 1) / NPART) + 3) & ~3;
    int beg = p * ep, endi = min(E, beg + ep);
    int cnt4 = (endi - beg) >> 2;
    for (int i = t; i < cnt4; i += 1024) {
        int e = beg + i * 4;
        int4 d = *(const int4*)(dst + e);
        int4 s = *(const int4*)(src + e);
        int p0 = atomicAdd(&sbase[d.x >> 6], 1);
        int p1 = atomicAdd(&sbase[d.y >> 6], 1);
        int p2 = atomicAdd(&sbase[d.z >> 6], 1);
        int p3 = atomicAdd(&sbase[d.w >> 6], 1);
        esA[p0] = ((d.x & 63) << 24) | s.x;
        esA[p1] = ((d.y & 63) << 24) | s.y;
        esA[p2] = ((d.z & 63) << 24) | s.z;
        esA[p3] = ((d.w & 63) << 24) | s.w;
    }
    int rem = (endi - beg) & 3;
    if (t < rem) {
        int e = beg + cnt4 * 4 + t;
        int d = dst[e];
        int pos = atomicAdd(&sbase[d >> 6], 1);
        esA[pos] = ((d & 63) << 24) | src[e];
    }
}

// ---------- scan over BP = B*NPART ----------

__global__ void k_blocksum(const int* __restrict__ cnt, int N, int* __restrict__ bsum) {
    __shared__ int sm[256];
    int b = blockIdx.x, t = threadIdx.x;
    int base = b * 1024 + t * 4;
    int s = 0;
#pragma unroll
    for (int i = 0; i < 4; ++i) { int j = base + i; if (j < N) s += cnt[j]; }
    sm[t] = s; __syncthreads();
    for (int off = 128; off > 0; off >>= 1) {
        if (t < off) sm[t] += sm[t + off];
        __syncthreads();
    }
    if (t == 0) bsum[b] = sm[0];
}

__global__ void k_scan_bsum(int* __restrict__ bsum, int nb, int* __restrict__ offN) {
    __shared__ int sm[1024];
    int t = threadIdx.x;
    int v = (t < nb) ? bsum[t] : 0;
    sm[t] = v; __syncthreads();
    for (int d = 1; d < 1024; d <<= 1) {
        int add = (t >= d) ? sm[t - d] : 0;
        __syncthreads();
        sm[t] += add;
        __syncthreads();
    }
    if (t < nb) bsum[t] = sm[t] - v;       // exclusive
    if (t == nb - 1) *offN = sm[t];        // total == E
}

__global__ void k_scan_block(const int* __restrict__ cnt, const int* __restrict__ bsum,
                             int* __restrict__ off, int N) {
    __shared__ int sm[256];
    int b = blockIdx.x, t = threadIdx.x;
    int base = b * 1024 + t * 4;
    int v[4];
#pragma unroll
    for (int i = 0; i < 4; ++i) { int j = base + i; v[i] = (j < N) ? cnt[j] : 0; }
    int tsum = v[0] + v[1] + v[2] + v[3];
    sm[t] = tsum; __syncthreads();
    for (int d = 1; d < 256; d <<= 1) {
        int val = (t >= d) ? sm[t - d] : 0;
        __syncthreads();
        sm[t] += val;
        __syncthreads();
    }
    int run = sm[t] - tsum + bsum[b];
#pragma unroll
    for (int i = 0; i < 4; ++i) {
        int j = base + i;
        if (j < N) off[j] = run;
        run += v[i];
    }
}

// ---------- per-bucket counting sort -> node-ordered edges + off[] + dinv[] ----------

__global__ __launch_bounds__(256) void k_bsort(const int* __restrict__ pbase, int BP,
                                               const int* __restrict__ esA,
                                               int* __restrict__ esB,
                                               int* __restrict__ off,
                                               float* __restrict__ dinv,
                                               int N, int E) {
    __shared__ int hcnt[64];
    __shared__ int hoff[64];
    int t = threadIdx.x, b = blockIdx.x;
    int start = pbase[b * NPART];
    int endi  = pbase[min((b + 1) * NPART, BP)];
    int cnt = endi - start;

    if (t < 64) hcnt[t] = 0;
    __syncthreads();
    for (int i = t * 4; i < cnt; i += 1024) {
#pragma unroll
        for (int c = 0; c < 4; ++c)
            if (i + c < cnt) atomicAdd(&hcnt[(esA[start + i + c] >> 24) & 63], 1);
    }
    __syncthreads();

    if (t < 64) {  // wave 0: 64-wide scan -> exclusive offsets
        int c = hcnt[t];
        int v = c;
#pragma unroll
        for (int d = 1; d < 64; d <<= 1) {
            int u = __shfl_up(v, d);
            if (t >= d) v += u;
        }
        int pos = start + (v - c);
        hoff[t] = pos;
        int g = b * 64 + t;
        if (g < N) {
            off[g] = pos;
            dinv[g] = rsqrtf((float)c + 1.0f);  // +1 self loop
        }
        if (g == N - 1) off[N] = E;
    }
    __syncthreads();
    if (t < 64) hcnt[t] = hoff[t];  // cursors
    __syncthreads();

    for (int i = t * 4; i < cnt; i += 1024) {
#pragma unroll
        for (int c = 0; c < 4; ++c)
            if (i + c < cnt) {
                int v = esA[start + i + c];
                int pos = atomicAdd(&hcnt[(v >> 24) & 63], 1);
                esB[pos] = v & 0xFFFFFF;
            }
    }
}

// ---------- GEMM: fp16 MFMA 16x16x32, fp32 accumulate ----------
// Block 256 = 4 waves; 64 rows/block; wave wv -> rows [16wv,16wv+16), all 64 cols.

template <int K, typename AT>
__global__ __launch_bounds__(256) void k_gemm(const AT* __restrict__ A,
                                              const float* __restrict__ W,
                                              const float* __restrict__ dinv,
                                              __half* __restrict__ hout, int N) {
    constexpr int ASTR = K + 8;
    __shared__ _Float16 a16[64 * ASTR];
    __shared__ _Float16 wt16[64 * ASTR];
    int t = threadIdx.x, lane = t & 63, wv = t >> 6;
    int rowBase = blockIdx.x * 64;

    // stage A rows -> fp16 (4 elems per thread-iter)
#pragma unroll
    for (int i = 0; i < K / 16; ++i) {
        int g = i * 256 + t;
        int r = g / (K / 4), kq = g % (K / 4);
        int gr = rowBase + r; if (gr >= N) gr = N - 1;
        _Float16* p = a16 + r * ASTR + kq * 4;
        if constexpr (sizeof(AT) == 4) {
            float4 v = *(const float4*)((const float*)A + (size_t)gr * K + kq * 4);
            *(__half2*)(p)     = __floats2half2_rn(v.x, v.y);
            *(__half2*)(p + 2) = __floats2half2_rn(v.z, v.w);
        } else {
            *(uint2*)p = *(const uint2*)((const __half*)A + (size_t)gr * K + kq * 4);
        }
    }
    // stage W^T -> fp16
#pragma unroll
    for (int i = 0; i < K / 16; ++i) {
        int g = i * 256 + t;
        int k = g >> 4, nq = g & 15;
        float4 v = *(const float4*)(W + (size_t)k * 64 + nq * 4);
        wt16[(nq * 4 + 0) * ASTR + k] = (_Float16)v.x;
        wt16[(nq * 4 + 1) * ASTR + k] = (_Float16)v.y;
        wt16[(nq * 4 + 2) * ASTR + k] = (_Float16)v.z;
        wt16[(nq * 4 + 3) * ASTR + k] = (_Float16)v.w;
    }
    __syncthreads();

    int m = lane & 15, q = lane >> 4;
    f4v acc[4] = {{0,0,0,0},{0,0,0,0},{0,0,0,0},{0,0,0,0}};
    const _Float16* arow = a16 + (wv * 16 + m) * ASTR + q * 8;
#pragma unroll
    for (int kt = 0; kt < K / 32; ++kt) {
        h8 af = *(const h8*)(arow + kt * 32);
#pragma unroll
        for (int nt = 0; nt < 4; ++nt) {
            h8 bf = *(const h8*)(wt16 + (nt * 16 + m) * ASTR + kt * 32 + q * 8);
            acc[nt] = __builtin_amdgcn_mfma_f32_16x16x32_f16(af, bf, acc[nt], 0, 0, 0);
        }
    }

    // epilogue: lane holds D[row=q*4+reg][col=nt*16+m]
    int r0 = rowBase + wv * 16 + q * 4;
#pragma unroll
    for (int reg = 0; reg < 4; ++reg) {
        int row = r0 + reg;
        if (row >= N) continue;
        float dv = dinv[row];
#pragma unroll
        for (int nt = 0; nt < 4; ++nt)
            hout[(size_t)row * 64 + nt * 16 + m] = (__half)(acc[nt][reg] * dv);
    }
}

// ---------- layer-1 aggregation: wave per node, fuses b0+lrelu, writes fp16 ----------
// lane = (qt, l16): group qt gathers edge rows; 16 lanes x uint2 = 128B per row.
// R3/R4: preload up to 64 edge indices with ONE coalesced esB load, distribute via
// __shfl; degree-branched chunks keep 4/8/8+8 gathers in flight, no esB in chain.

__global__ __launch_bounds__(256) void k_agg1(const int* __restrict__ off,
                                              const int* __restrict__ esB,
                                              const float* __restrict__ dinv,
                                              const __half* __restrict__ hs,
                                              const float* __restrict__ b0,
                                              __half* __restrict__ aout, int N) {
    int lane = threadIdx.x & 63;
    int node = (blockIdx.x * blockDim.x + threadIdx.x) >> 6;
    if (node >= N) return;
    int qt = lane >> 4, l16 = lane & 15;
    int beg = off[node], end = off[node + 1];
    float dv = dinv[node];                       // hoisted
    float4 b = *(const float4*)(b0 + l16 * 4);   // hoisted

    float ax = 0, ay = 0, az = 0, aw = 0;
    auto ld = [&](int s) { return *(const uint2*)(hs + (size_t)s * 64 + l16 * 4); };
    auto acc4 = [&](uint2 u) {
        float2 f0 = __half22float2(*(__half2*)&u.x);
        float2 f1 = __half22float2(*(__half2*)&u.y);
        ax += f0.x; ay += f0.y; az += f1.x; aw += f1.y;
    };
    if (qt == 0) acc4(ld(node));  // self loop (issued first, overlaps edge idx load)

    for (int base = beg; base < end; base += 64) {
        int nb = min(end - base, 64);                   // wave-uniform
        int myIdx = esB[min(base + lane, end - 1)];     // ONE coalesced idx load
        if (nb <= 16) {                                  // 4 gathers/group in flight
            int s0 = __shfl(myIdx, min(qt,      nb - 1));
            int s1 = __shfl(myIdx, min(qt + 4,  nb - 1));
            int s2 = __shfl(myIdx, min(qt + 8,  nb - 1));
            int s3 = __shfl(myIdx, min(qt + 12, nb - 1));
            uint2 u0 = ld(s0), u1 = ld(s1), u2 = ld(s2), u3 = ld(s3);
            if (qt      < nb) acc4(u0);
            if (qt + 4  < nb) acc4(u1);
            if (qt + 8  < nb) acc4(u2);
            if (qt + 12 < nb) acc4(u3);
        } else {                                         // 8 gathers/group in flight
            int s0 = __shfl(myIdx, min(qt,      nb - 1));
            int s1 = __shfl(myIdx, min(qt + 4,  nb - 1));
            int s2 = __shfl(myIdx, min(qt + 8,  nb - 1));
            int s3 = __shfl(myIdx, min(qt + 12, nb - 1));
            int s4 = __shfl(myIdx, min(qt + 16, nb - 1));
            int s5 = __shfl(myIdx, min(qt + 20, nb - 1));
            int s6 = __shfl(myIdx, min(qt + 24, nb - 1));
            int s7 = __shfl(myIdx, min(qt + 28, nb - 1));
            uint2 u0 = ld(s0), u1 = ld(s1), u2 = ld(s2), u3 = ld(s3);
            uint2 u4 = ld(s4), u5 = ld(s5), u6 = ld(s6), u7 = ld(s7);
            acc4(u0);                                    // qt < 4 <= 16 < nb: safe
            if (qt + 4  < nb) acc4(u1);
            if (qt + 8  < nb) acc4(u2);
            if (qt + 12 < nb) acc4(u3);
            if (qt + 16 < nb) acc4(u4);
            if (qt + 20 < nb) acc4(u5);
            if (qt + 24 < nb) acc4(u6);
            if (qt + 28 < nb) acc4(u7);
            if (nb > 32) {                               // second 8-chunk (deg 33..64)
                int t0 = __shfl(myIdx, min(qt + 32, nb - 1));
                int t1 = __shfl(myIdx, min(qt + 36, nb - 1));
                int t2 = __shfl(myIdx, min(qt + 40, nb - 1));
                int t3 = __shfl(myIdx, min(qt + 44, nb - 1));
                int t4 = __shfl(myIdx, min(qt + 48, nb - 1));
                int t5 = __shfl(myIdx, min(qt + 52, nb - 1));
                int t6 = __shfl(myIdx, min(qt + 56, nb - 1));
                int t7 = __shfl(myIdx, min(qt + 60, nb - 1));
                uint2 v0 = ld(t0), v1 = ld(t1), v2 = ld(t2), v3 = ld(t3);
                uint2 v4 = ld(t4), v5 = ld(t5), v6 = ld(t6), v7 = ld(t7);
                if (qt + 32 < nb) acc4(v0);              // predicate slot qt+32
                if (qt + 36 < nb) acc4(v1);
                if (qt + 40 < nb) acc4(v2);
                if (qt + 44 < nb) acc4(v3);
                if (qt + 48 < nb) acc4(v4);
                if (qt + 52 < nb) acc4(v5);
                if (qt + 56 < nb) acc4(v6);
                if (qt + 60 < nb) acc4(v7);
            }
        }
    }

#pragma unroll
    for (int d = 16; d <= 32; d <<= 1) {
        ax += __shfl_xor(ax, d); ay += __shfl_xor(ay, d);
        az += __shfl_xor(az, d); aw += __shfl_xor(aw, d);
    }
    if (qt == 0) {
        float ox = lrelu(ax * dv + b.x), oy = lrelu(ay * dv + b.y);
        float oz = lrelu(az * dv + b.z), ow = lrelu(aw * dv + b.w);
        uint2 u;
        *(__half2*)&u.x = __floats2half2_rn(ox, oy);
        *(__half2*)&u.y = __floats2half2_rn(oz, ow);
        *(uint2*)(aout + (size_t)node * 64 + l16 * 4) = u;
    }
}

// ---------- fused selected-node layer-2 agg + b1 + lrelu + head + sigmoid ----------
// wave per output slot: node=idx[wv]; gather its edges only (~20% of E total).

__global__ __launch_bounds__(256) void k_aggout(const int* __restrict__ idx,
                                                const int* __restrict__ off,
                                                const int* __restrict__ esB,
                                                const float* __restrict__ dinv,
                                                const __half* __restrict__ hs,
                                                const float* __restrict__ b1,
                                                const float* __restrict__ Wm,
                                                const float* __restrict__ bm,
                                                float* __restrict__ out, int NSEL) {
    int lane = threadIdx.x & 63;
    int wv = (blockIdx.x * blockDim.x + threadIdx.x) >> 6;
    if (wv >= NSEL) return;
    int node = idx[wv];
    int qt = lane >> 4, l16 = lane & 15;
    int beg = off[node], end = off[node + 1];
    float dv = dinv[node];                       // hoisted
    float4 b = *(const float4*)(b1 + l16 * 4);   // hoisted

    float ax = 0, ay = 0, az = 0, aw = 0;
    auto ld = [&](int s) { return *(const uint2*)(hs + (size_t)s * 64 + l16 * 4); };
    auto acc4 = [&](uint2 u) {
        float2 f0 = __half22float2(*(__half2*)&u.x);
        float2 f1 = __half22float2(*(__half2*)&u.y);
        ax += f0.x; ay += f0.y; az += f1.x; aw += f1.y;
    };
    if (qt == 0) acc4(ld(node));  // self loop

    for (int base = beg; base < end; base += 64) {
        int nb = min(end - base, 64);
        int myIdx = esB[min(base + lane, end - 1)];
        if (nb <= 16) {
            int s0 = __shfl(myIdx, min(qt,      nb - 1));
            int s1 = __shfl(myIdx, min(qt + 4,  nb - 1));
            int s2 = __shfl(myIdx, min(qt + 8,  nb - 1));
            int s3 = __shfl(myIdx, min(qt + 12, nb - 1));
            uint2 u0 = ld(s0), u1 = ld(s1), u2 = ld(s2), u3 = ld(s3);
            if (qt      < nb) acc4(u0);
            if (qt + 4  < nb) acc4(u1);
            if (qt + 8  < nb) acc4(u2);
            if (qt + 12 < nb) acc4(u3);
        } else {
            int s0 = __shfl(myIdx, min(qt,      nb - 1));
            int s1 = __shfl(myIdx, min(qt + 4,  nb - 1));
            int s2 = __shfl(myIdx, min(qt + 8,  nb - 1));
            int s3 = __shfl(myIdx, min(qt + 12, nb - 1));
            int s4 = __shfl(myIdx, min(qt + 16, nb - 1));
            int s5 = __shfl(myIdx, min(qt + 20, nb - 1));
            int s6 = __shfl(myIdx, min(qt + 24, nb - 1));
            int s7 = __shfl(myIdx, min(qt + 28, nb - 1));
            uint2 u0 = ld(s0), u1 = ld(s1), u2 = ld(s2), u3 = ld(s3);
            uint2 u4 = ld(s4), u5 = ld(s5), u6 = ld(s6), u7 = ld(s7);
            acc4(u0);
            if (qt + 4  < nb) acc4(u1);
            if (qt + 8  < nb) acc4(u2);
            if (qt + 12 < nb) acc4(u3);
            if (qt + 16 < nb) acc4(u4);
            if (qt + 20 < nb) acc4(u5);
            if (qt + 24 < nb) acc4(u6);
            if (qt + 28 < nb) acc4(u7);
            if (nb > 32) {
                int t0 = __shfl(myIdx, min(qt + 32, nb - 1));
                int t1 = __shfl(myIdx, min(qt + 36, nb - 1));
                int t2 = __shfl(myIdx, min(qt + 40, nb - 1));
                int t3 = __shfl(myIdx, min(qt + 44, nb - 1));
                int t4 = __shfl(myIdx, min(qt + 48, nb - 1));
                int t5 = __shfl(myIdx, min(qt + 52, nb - 1));
                int t6 = __shfl(myIdx, min(qt + 56, nb - 1));
                int t7 = __shfl(myIdx, min(qt + 60, nb - 1));
                uint2 v0 = ld(t0), v1 = ld(t1), v2 = ld(t2), v3 = ld(t3);
                uint2 v4 = ld(t4), v5 = ld(t5), v6 = ld(t6), v7 = ld(t7);
                if (qt + 32 < nb) acc4(v0);
                if (qt + 36 < nb) acc4(v1);
                if (qt + 40 < nb) acc4(v2);
                if (qt + 44 < nb) acc4(v3);
                if (qt + 48 < nb) acc4(v4);
                if (qt + 52 < nb) acc4(v5);
                if (qt + 56 < nb) acc4(v6);
                if (qt + 60 < nb) acc4(v7);
            }
        }
    }

#pragma unroll
    for (int d = 16; d <= 32; d <<= 1) {  // all lanes end with full sums
        ax += __shfl_xor(ax, d); ay += __shfl_xor(ay, d);
        az += __shfl_xor(az, d); aw += __shfl_xor(aw, d);
    }

    float4 hsel;
    hsel.x = lrelu(ax * dv + b.x); hsel.y = lrelu(ay * dv + b.y);
    hsel.z = lrelu(az * dv + b.z); hsel.w = lrelu(aw * dv + b.w);
    if (qt == 0) *(float4*)(out + (size_t)wv * 64 + l16 * 4) = hsel;

    // head: p[o] = sum_c hsel_c * Wm[c][o]; channels 4*l16..4*l16+3 on each lane
    const float* wr = Wm + (size_t)(4 * l16) * 5;
#pragma unroll
    for (int o = 0; o < 5; ++o) {
        float p = hsel.x * wr[o] + hsel.y * wr[5 + o] +
                  hsel.z * wr[10 + o] + hsel.w * wr[15 + o];
        p += __shfl_xor(p, 1); p += __shfl_xor(p, 2);
        p += __shfl_xor(p, 4); p += __shfl_xor(p, 8);
        if (lane == 0)
            out[(size_t)NSEL * 64 + (size_t)wv * 5 + o] =
                1.0f / (1.0f + expf(-(p + bm[o])));
    }
}

extern "C" void kernel_launch(void* const* d_in, const int* in_sizes, int n_in,
                              void* d_out, int out_size, void* d_ws, size_t ws_size,
                              hipStream_t stream) {
    const float* x   = (const float*)d_in[0];
    const int*   ei  = (const int*)d_in[1];
    const int*   idx = (const int*)d_in[2];
    const float* W0  = (const float*)d_in[3];
    const float* b0  = (const float*)d_in[4];
    const float* W1  = (const float*)d_in[5];
    const float* b1  = (const float*)d_in[6];
    const float* Wm  = (const float*)d_in[7];
    const float* bm  = (const float*)d_in[8];

    int N    = in_sizes[0] / 128;
    int E    = in_sizes[1] / 2;
    int NSEL = in_sizes[2];
    const int* src = ei;
    const int* dst = ei + E;

    int B  = (N + 63) / 64;
    int BP = B * NPART;

    char* w = (char*)d_ws;
    size_t Na  = ((size_t)N + 1023) & ~(size_t)1023;
    size_t Ea  = ((size_t)E + 1023) & ~(size_t)1023;
    size_t BPa = ((size_t)BP + 1023) & ~(size_t)1023;
    float*  dinv  = (float*)w;                w += Na * 4;
    int*    phist = (int*)w;                  w += BPa * 4;
    int*    pbase = (int*)w;                  w += (BPa + 1024) * 4;
    int*    bsum  = (int*)w;                  w += 1024 * 4;
    int*    off   = (int*)w;                  w += (Na + 1024) * 4;
    int*    esA   = (int*)w;                  w += Ea * 4;
    int*    esB   = (int*)w;                  w += Ea * 4;
    __half* hs16  = (__half*)w;               w += (size_t)N * 64 * 2;  // h*dinv (layer in/out)
    __half* a16g  = (__half*)w;                                        // lrelu(agg1+b0), fp16

    int nbp = (BP + 1023) / 1024;

    k_part_hist<<<NPART, 1024, 0, stream>>>(dst, E, B, phist);
    k_blocksum<<<nbp, 256, 0, stream>>>(phist, BP, bsum);
    k_scan_bsum<<<1, 1024, 0, stream>>>(bsum, nbp, pbase + BP);
    k_scan_block<<<nbp, 256, 0, stream>>>(phist, bsum, pbase, BP);
    k_part_scatter<<<NPART, 1024, 0, stream>>>(src, dst, E, B, pbase, esA);
    k_bsort<<<B, 256, 0, stream>>>(pbase, BP, esA, esB, off, dinv, N, E);

    int gemm_blocks = (N + 63) / 64;
    int agg_blocks  = (N + 3) / 4;

    k_gemm<128, float><<<gemm_blocks, 256, 0, stream>>>(x, W0, dinv, hs16, N);
    k_agg1<<<agg_blocks, 256, 0, stream>>>(off, esB, dinv, hs16, b0, a16g, N);
    k_gemm<64, __half><<<gemm_blocks, 256, 0, stream>>>(a16g, W1, dinv, hs16, N);
    k_aggout<<<(NSEL + 3) / 4, 256, 0, stream>>>(idx, off, esB, dinv, hs16, b1, Wm, bm,
                                                 (float*)d_out, NSEL);
}